// Round 1
// baseline (210.701 us; speedup 1.0000x reference)
//
#include <hip/hip_runtime.h>
#include <hip/hip_bf16.h>
#include <cstdint>

// TripCenterLoss_min_margin: B=8192 batch, C=4096 classes, D=2048 feat
// loss = mean_b max(margin + w*dist_own(b) - (1-w)*min_{c!=lbl} dist(b,c), 0)
// dist(b,c) = ||x_b||^2 + ||cen_c||^2 - 2 x_b.cen_c
constexpr int NB = 8192;
constexpr int NC = 4096;
constexpr int ND = 2048;

constexpr int BM = 128, BN = 128, BK = 32;
constexpr int NRB = NB / BM;    // 64 row blocks
constexpr int NCB = NC / BN;    // 32 col blocks
constexpr int NWG = NRB * NCB;  // 2048
constexpr int NSLOT = NC / 64;  // 64 pmin slots per row (one per 64-col wave tile)

typedef __attribute__((ext_vector_type(8))) __bf16 bf16x8;
typedef __attribute__((ext_vector_type(8))) unsigned short ushort8;
typedef __attribute__((ext_vector_type(4))) float f32x4;

__device__ inline unsigned short f2bf(float f) {
  unsigned int u = __float_as_uint(f);
  u += 0x7fffu + ((u >> 16) & 1u);  // round-to-nearest-even
  return (unsigned short)(u >> 16);
}

// ---------------- row norms (f32, exact) ----------------
__global__ __launch_bounds__(256) void norms_kernel(const float* __restrict__ x,
                                                    const float* __restrict__ cen,
                                                    float* __restrict__ xnorm,
                                                    float* __restrict__ cnorm) {
  int row = blockIdx.x;
  const float* src;
  float* dst;
  if (row < NB) { src = x + (size_t)row * ND; dst = xnorm + row; }
  else          { src = cen + (size_t)(row - NB) * ND; dst = cnorm + (row - NB); }
  float s = 0.f;
  #pragma unroll
  for (int it = 0; it < 2; it++) {
    int i = threadIdx.x * 4 + it * 1024;
    float4 v = *(const float4*)(src + i);
    s += v.x * v.x + v.y * v.y + v.z * v.z + v.w * v.w;
  }
  #pragma unroll
  for (int m = 1; m < 64; m <<= 1) s += __shfl_xor(s, m);
  __shared__ float red[4];
  int lane = threadIdx.x & 63, wid = threadIdx.x >> 6;
  if (lane == 0) red[wid] = s;
  __syncthreads();
  if (threadIdx.x == 0) *dst = red[0] + red[1] + red[2] + red[3];
}

// ---------------- f32 -> bf16 convert (RNE), vectorized ----------------
__global__ __launch_bounds__(256) void convert_kernel(const float* __restrict__ in,
                                                      unsigned short* __restrict__ out,
                                                      int n) {
  int stride = gridDim.x * 256 * 8;
  for (int i = (blockIdx.x * 256 + threadIdx.x) * 8; i < n; i += stride) {
    float4 a = *(const float4*)(in + i);
    float4 b = *(const float4*)(in + i + 4);
    ushort8 u;
    u[0] = f2bf(a.x); u[1] = f2bf(a.y); u[2] = f2bf(a.z); u[3] = f2bf(a.w);
    u[4] = f2bf(b.x); u[5] = f2bf(b.y); u[6] = f2bf(b.z); u[7] = f2bf(b.w);
    *(ushort8*)(out + i) = u;
  }
}

// ---------------- async global->LDS helper ----------------
__device__ inline void gload_lds16(const void* g, void* lds) {
  __builtin_amdgcn_global_load_lds(
      (const __attribute__((address_space(1))) unsigned int*)g,
      (__attribute__((address_space(3))) unsigned int*)lds, 16, 0, 0);
}

// ---------------- fused GEMM + row-min + own-dist ----------------
// Tile 128x128, BK=32, 4 waves in 2x2, each wave 64x64 (4x4 frags of 16x16x32).
// PRE=true : stage bf16 tiles from preconverted ws via global_load_lds (16B).
// PRE=false: reg-stage f32 from inputs, convert to bf16, ds_write.
template <bool PRE>
__global__ __launch_bounds__(256) void gemm_min_kernel(
    const float* __restrict__ xf, const float* __restrict__ cf,
    const unsigned short* __restrict__ xb, const unsigned short* __restrict__ cb,
    const float* __restrict__ xnorm, const float* __restrict__ cnorm,
    const int* __restrict__ labels,
    float* __restrict__ own, float* __restrict__ pmin) {
  __shared__ alignas(16) unsigned short lA[BM * BK];  // [row][k] row-major, 8KB
  __shared__ alignas(16) unsigned short lB[BN * BK];  // [col][k] row-major, 8KB

  const int tid = threadIdx.x;
  const int lane = tid & 63;
  const int wid = tid >> 6;

  // XCD-aware swizzle (2048 % 8 == 0 -> bijective)
  int bid = blockIdx.x;
  int swz = (bid & 7) * (NWG >> 3) + (bid >> 3);
  int rb = swz / NCB;
  int cbk = swz % NCB;
  const int brow0 = rb * BM;
  const int bcol0 = cbk * BN;

  const int wr = wid >> 1, wc = wid & 1;  // 2x2 wave grid

  f32x4 acc[4][4];
  #pragma unroll
  for (int m = 0; m < 4; m++)
    #pragma unroll
    for (int n = 0; n < 4; n++)
      acc[m][n] = (f32x4){0.f, 0.f, 0.f, 0.f};

  for (int k0 = 0; k0 < ND; k0 += BK) {
    __syncthreads();  // protect LDS from previous iteration's readers
    if constexpr (PRE) {
      // 8KB per tile / 256 thr / 16B = 2 loads each for A and B.
      // LDS dest must be wave-uniform base + lane*16 (linear layout).
      #pragma unroll
      for (int i = 0; i < 2; i++) {
        int off = wid * 2048 + i * 1024 + lane * 16;  // byte offset in tile
        int row = off >> 6;                            // 64B per 32-elem row
        int col = (off & 63) >> 1;                     // bf16 element col
        gload_lds16(xb + (size_t)(brow0 + row) * ND + k0 + col, (char*)lA + off);
        gload_lds16(cb + (size_t)(bcol0 + row) * ND + k0 + col, (char*)lB + off);
      }
    } else {
      // reg-stage: 16 consecutive f32 per thread per tile, convert, 2x16B ds_write
      int ar = tid >> 1;
      int ac = (tid & 1) << 4;
      const float* ga = xf + (size_t)(brow0 + ar) * ND + k0 + ac;
      const float* gb = cf + (size_t)(bcol0 + ar) * ND + k0 + ac;
      float4 a0 = *(const float4*)ga;
      float4 a1 = *(const float4*)(ga + 4);
      float4 a2 = *(const float4*)(ga + 8);
      float4 a3 = *(const float4*)(ga + 12);
      float4 b0 = *(const float4*)gb;
      float4 b1 = *(const float4*)(gb + 4);
      float4 b2 = *(const float4*)(gb + 8);
      float4 b3 = *(const float4*)(gb + 12);
      ushort8 ua0, ua1, ub0, ub1;
      ua0[0] = f2bf(a0.x); ua0[1] = f2bf(a0.y); ua0[2] = f2bf(a0.z); ua0[3] = f2bf(a0.w);
      ua0[4] = f2bf(a1.x); ua0[5] = f2bf(a1.y); ua0[6] = f2bf(a1.z); ua0[7] = f2bf(a1.w);
      ua1[0] = f2bf(a2.x); ua1[1] = f2bf(a2.y); ua1[2] = f2bf(a2.z); ua1[3] = f2bf(a2.w);
      ua1[4] = f2bf(a3.x); ua1[5] = f2bf(a3.y); ua1[6] = f2bf(a3.z); ua1[7] = f2bf(a3.w);
      ub0[0] = f2bf(b0.x); ub0[1] = f2bf(b0.y); ub0[2] = f2bf(b0.z); ub0[3] = f2bf(b0.w);
      ub0[4] = f2bf(b1.x); ub0[5] = f2bf(b1.y); ub0[6] = f2bf(b1.z); ub0[7] = f2bf(b1.w);
      ub1[0] = f2bf(b2.x); ub1[1] = f2bf(b2.y); ub1[2] = f2bf(b2.z); ub1[3] = f2bf(b2.w);
      ub1[4] = f2bf(b3.x); ub1[5] = f2bf(b3.y); ub1[6] = f2bf(b3.z); ub1[7] = f2bf(b3.w);
      *(ushort8*)&lA[ar * BK + ac] = ua0;
      *(ushort8*)&lA[ar * BK + ac + 8] = ua1;
      *(ushort8*)&lB[ar * BK + ac] = ub0;
      *(ushort8*)&lB[ar * BK + ac + 8] = ub1;
    }
    __syncthreads();  // full drain: staged data visible

    // fragments: lane holds row/col = lane&15, k = (lane>>4)*8 + [0..7]
    // (A and B use the IDENTICAL position->k scheme -> any internal K
    //  permutation by the HW cancels; only C/D layout matters, m89-verified)
    bf16x8 af[4], bfr[4];
    #pragma unroll
    for (int m = 0; m < 4; m++)
      af[m] = *(const bf16x8*)&lA[(wr * 64 + m * 16 + (lane & 15)) * BK + (lane >> 4) * 8];
    #pragma unroll
    for (int n = 0; n < 4; n++)
      bfr[n] = *(const bf16x8*)&lB[(wc * 64 + n * 16 + (lane & 15)) * BK + (lane >> 4) * 8];
    #pragma unroll
    for (int m = 0; m < 4; m++)
      #pragma unroll
      for (int n = 0; n < 4; n++)
        acc[m][n] = __builtin_amdgcn_mfma_f32_16x16x32_bf16(af[m], bfr[n], acc[m][n], 0, 0, 0);
  }

  // ---- epilogue: dist = xn + cn - 2*dot; own-col extract; per-row min ----
  // C/D layout (verified): col = lane&15, row = (lane>>4)*4 + reg
  const int llo = lane & 15, lhi = lane >> 4;
  float cnr[4];
  int coln[4];
  #pragma unroll
  for (int n = 0; n < 4; n++) {
    coln[n] = bcol0 + wc * 64 + n * 16 + llo;
    cnr[n] = cnorm[coln[n]];
  }
  const int cslot = cbk * 2 + wc;
  #pragma unroll
  for (int m = 0; m < 4; m++) {
    #pragma unroll
    for (int j = 0; j < 4; j++) {
      int row = brow0 + wr * 64 + m * 16 + lhi * 4 + j;
      float xn = xnorm[row];
      int lbl = labels[row];
      float rmin = 1e38f;
      #pragma unroll
      for (int n = 0; n < 4; n++) {
        float d = xn + cnr[n] - 2.0f * acc[m][n][j];
        if (coln[n] == lbl) own[row] = d;  // exactly one writer per row
        else rmin = fminf(rmin, d);
      }
      // reduce min over the 16 lanes holding this row (xor bits 0-3)
      rmin = fminf(rmin, __shfl_xor(rmin, 1));
      rmin = fminf(rmin, __shfl_xor(rmin, 2));
      rmin = fminf(rmin, __shfl_xor(rmin, 4));
      rmin = fminf(rmin, __shfl_xor(rmin, 8));
      if (llo == 0) pmin[(size_t)row * NSLOT + cslot] = rmin;
    }
  }
}

// ---------------- final: hinge + deterministic sum ----------------
__global__ __launch_bounds__(256) void finalize_kernel(const float* __restrict__ own,
                                                       const float* __restrict__ pmin,
                                                       const float* __restrict__ margin,
                                                       const float* __restrict__ wgt,
                                                       float* __restrict__ partial) {
  int r = blockIdx.x * 256 + threadIdx.x;
  const float4* p4 = (const float4*)(pmin + (size_t)r * NSLOT);
  float mn = 1e38f;
  #pragma unroll
  for (int i = 0; i < NSLOT / 4; i++) {
    float4 v = p4[i];
    mn = fminf(mn, fminf(fminf(v.x, v.y), fminf(v.z, v.w)));
  }
  float W = *wgt;
  float h = fmaxf(*margin + W * own[r] - (1.0f - W) * mn, 0.0f);
  #pragma unroll
  for (int m = 1; m < 64; m <<= 1) h += __shfl_xor(h, m);
  __shared__ float red[4];
  int lane = threadIdx.x & 63, wid = threadIdx.x >> 6;
  if (lane == 0) red[wid] = h;
  __syncthreads();
  if (threadIdx.x == 0) partial[blockIdx.x] = red[0] + red[1] + red[2] + red[3];
}

__global__ void final2_kernel(const float* __restrict__ partial, float* __restrict__ out) {
  float s = (threadIdx.x < NB / 256) ? partial[threadIdx.x] : 0.f;
  #pragma unroll
  for (int m = 1; m < 64; m <<= 1) s += __shfl_xor(s, m);
  if (threadIdx.x == 0) out[0] = s * (1.0f / NB);
}

extern "C" void kernel_launch(void* const* d_in, const int* in_sizes, int n_in,
                              void* d_out, int out_size, void* d_ws, size_t ws_size,
                              hipStream_t stream) {
  const float* x = (const float*)d_in[0];
  const float* cen = (const float*)d_in[1];
  const int* labels = (const int*)d_in[2];
  const float* margin = (const float*)d_in[3];
  const float* wgt = (const float*)d_in[4];
  float* out = (float*)d_out;

  char* base = (char*)d_ws;
  size_t off = 0;
  auto alloc = [&](size_t bytes) {
    void* q = base + off;
    off = (off + bytes + 255) & ~(size_t)255;
    return q;
  };
  float* xnorm = (float*)alloc((size_t)NB * 4);
  float* cnorm = (float*)alloc((size_t)NC * 4);
  float* own = (float*)alloc((size_t)NB * 4);
  float* pmin = (float*)alloc((size_t)NB * NSLOT * 4);
  float* partial = (float*)alloc(64 * 4);
  unsigned short* xb = (unsigned short*)alloc((size_t)NB * ND * 2);
  unsigned short* cb = (unsigned short*)alloc((size_t)NC * ND * 2);
  size_t need_big = off;  // ~52.6 MB

  norms_kernel<<<NB + NC, 256, 0, stream>>>(x, cen, xnorm, cnorm);

  if (ws_size >= need_big) {
    convert_kernel<<<1024, 256, 0, stream>>>(x, xb, NB * ND);
    convert_kernel<<<1024, 256, 0, stream>>>(cen, cb, NC * ND);
    gemm_min_kernel<true><<<NWG, 256, 0, stream>>>(x, cen, xb, cb, xnorm, cnorm,
                                                   labels, own, pmin);
  } else {
    gemm_min_kernel<false><<<NWG, 256, 0, stream>>>(x, cen, nullptr, nullptr, xnorm,
                                                    cnorm, labels, own, pmin);
  }
  finalize_kernel<<<NB / 256, 256, 0, stream>>>(own, pmin, margin, wgt, partial);
  final2_kernel<<<1, 64, 0, stream>>>(partial, out);
}

// Round 3
// 168.251 us; speedup vs baseline: 1.2523x; 1.2523x over previous
//
#include <hip/hip_runtime.h>
#include <hip/hip_bf16.h>
#include <cstdint>

// TripCenterLoss_min_margin: B=8192, C=4096, D=2048
// loss = mean_b max(margin + w*dist_own(b) - (1-w)*min_{c!=lbl} dist(b,c), 0)
constexpr int NB = 8192;
constexpr int NC = 4096;
constexpr int ND = 2048;

// ---- 8-phase 256x256 GEMM geometry ----
constexpr int BM = 256, BN = 256, BK = 64;
constexpr int NRB = NB / BM;    // 32
constexpr int NCB = NC / BN;    // 16
constexpr int NWG = NRB * NCB;  // 512  (%8==0 -> bijective XCD swizzle)
constexpr int NT = ND / BK;     // 32 K-tiles
constexpr int NIT = NT / 2;     // 16 iterations (2 K-tiles each)
constexpr int NSLOT = NC / 64;  // 64 pmin slots per row

typedef __attribute__((ext_vector_type(8))) __bf16 bf16x8;
typedef __attribute__((ext_vector_type(8))) unsigned short usvec8;
typedef __attribute__((ext_vector_type(4))) unsigned short usvec4;
typedef __attribute__((ext_vector_type(4))) float f32x4;

__device__ inline unsigned short f2bf(float f) {
  unsigned int u = __float_as_uint(f);
  u += 0x7fffu + ((u >> 16) & 1u);  // RNE
  return (unsigned short)(u >> 16);
}

// ---------------- fused norms + f32->bf16 convert ----------------
__global__ __launch_bounds__(256) void prep_kernel(const float* __restrict__ x,
                                                   const float* __restrict__ cen,
                                                   float* __restrict__ xnorm,
                                                   float* __restrict__ cnorm,
                                                   unsigned short* __restrict__ xb,
                                                   unsigned short* __restrict__ cb) {
  int row = blockIdx.x;
  const float* src;
  float* ndst;
  unsigned short* bdst;
  if (row < NB) { src = x + (size_t)row * ND; ndst = xnorm + row; bdst = xb + (size_t)row * ND; }
  else { row -= NB; src = cen + (size_t)row * ND; ndst = cnorm + row; bdst = cb + (size_t)row * ND; }
  float s = 0.f;
  #pragma unroll
  for (int it = 0; it < 2; it++) {
    int i = threadIdx.x * 4 + it * 1024;
    float4 v = *(const float4*)(src + i);
    s += v.x * v.x + v.y * v.y + v.z * v.z + v.w * v.w;
    usvec4 u;
    u[0] = f2bf(v.x); u[1] = f2bf(v.y); u[2] = f2bf(v.z); u[3] = f2bf(v.w);
    *(usvec4*)(bdst + i) = u;
  }
  #pragma unroll
  for (int m = 1; m < 64; m <<= 1) s += __shfl_xor(s, m);
  __shared__ float red[4];
  int lane = threadIdx.x & 63, wid = threadIdx.x >> 6;
  if (lane == 0) red[wid] = s;
  __syncthreads();
  if (threadIdx.x == 0) *ndst = red[0] + red[1] + red[2] + red[3];
}

// ---------------- norms only (fallback path) ----------------
__global__ __launch_bounds__(256) void norms_kernel(const float* __restrict__ x,
                                                    const float* __restrict__ cen,
                                                    float* __restrict__ xnorm,
                                                    float* __restrict__ cnorm) {
  int row = blockIdx.x;
  const float* src;
  float* dst;
  if (row < NB) { src = x + (size_t)row * ND; dst = xnorm + row; }
  else          { src = cen + (size_t)(row - NB) * ND; dst = cnorm + (row - NB); }
  float s = 0.f;
  #pragma unroll
  for (int it = 0; it < 2; it++) {
    int i = threadIdx.x * 4 + it * 1024;
    float4 v = *(const float4*)(src + i);
    s += v.x * v.x + v.y * v.y + v.z * v.z + v.w * v.w;
  }
  #pragma unroll
  for (int m = 1; m < 64; m <<= 1) s += __shfl_xor(s, m);
  __shared__ float red[4];
  int lane = threadIdx.x & 63, wid = threadIdx.x >> 6;
  if (lane == 0) red[wid] = s;
  __syncthreads();
  if (threadIdx.x == 0) *dst = red[0] + red[1] + red[2] + red[3];
}

// ---------------- async global->LDS ----------------
__device__ inline void gload_lds16(const void* g, void* lds) {
  __builtin_amdgcn_global_load_lds(
      (const __attribute__((address_space(1))) unsigned int*)g,
      (__attribute__((address_space(3))) unsigned int*)lds, 16, 0, 0);
}

// Stage one half-tile (256 rows x 32 k, 16KB) into a contiguous LDS region.
// LDS dest is LINEAR (base + chunk*16); the XOR swizzle (kc ^= row&3) is applied
// by permuting the GLOBAL source address (involution), per rule 21.
__device__ __forceinline__ void stage_half(unsigned short* reg, const unsigned short* gsrc,
                                           int row0, int kcol0, int wid, int lane) {
  #pragma unroll
  for (int i = 0; i < 2; i++) {
    int c = (wid * 2 + i) * 64 + lane;   // chunk index 0..1023
    int row = c >> 2;                    // 4 chunks (64B) per row
    int kc = (c & 3) ^ (row & 3);        // logical k-chunk stored at this physical slot
    gload_lds16(gsrc + (size_t)(row0 + row) * ND + kcol0 + kc * 8,
                (char*)reg + (size_t)c * 16);
  }
}

// One phase: ds-read frag subtile | issue 1 half-tile stage | barrier |
// lgkmcnt(0) | setprio(1) | 16 MFMA | setprio(0) | [vmcnt] | barrier.
#define PHASE(BUF, S, NH, STAGE_STMT, VM_STMT)                                          \
  {                                                                                     \
    const char* Ar = (const char*)&lds[BUF][0][S][0];                                   \
    const char* Br = (const char*)&lds[BUF][1][S][0];                                   \
    if (NH == 0) {                                                                      \
      _Pragma("unroll") for (int m = 0; m < 8; m++)                                     \
          afr[m] = *(const bf16x8*)(Ar + (wr * 128 + m * 16 + llo) * 64 + sw);          \
    }                                                                                   \
    bf16x8 b0 = *(const bf16x8*)(Br + (wc * 64 + (NH * 2 + 0) * 16 + llo) * 64 + sw);   \
    bf16x8 b1 = *(const bf16x8*)(Br + (wc * 64 + (NH * 2 + 1) * 16 + llo) * 64 + sw);   \
    STAGE_STMT;                                                                         \
    __builtin_amdgcn_s_barrier();                                                       \
    asm volatile("s_waitcnt lgkmcnt(0)" ::: "memory");                                  \
    __builtin_amdgcn_sched_barrier(0);                                                  \
    __builtin_amdgcn_s_setprio(1);                                                      \
    _Pragma("unroll") for (int m = 0; m < 8; m++) {                                     \
      acc[m][NH * 2 + 0] = __builtin_amdgcn_mfma_f32_16x16x32_bf16(                     \
          afr[m], b0, acc[m][NH * 2 + 0], 0, 0, 0);                                     \
      acc[m][NH * 2 + 1] = __builtin_amdgcn_mfma_f32_16x16x32_bf16(                     \
          afr[m], b1, acc[m][NH * 2 + 1], 0, 0, 0);                                     \
    }                                                                                   \
    __builtin_amdgcn_s_setprio(0);                                                      \
    VM_STMT;                                                                            \
    __builtin_amdgcn_s_barrier();                                                       \
  }

// ---------------- 8-phase 256^2 fused GEMM + row-min + own-dist ----------------
__global__ __launch_bounds__(512, 2) void gemm8_kernel(
    const unsigned short* __restrict__ xb, const unsigned short* __restrict__ cb,
    const float* __restrict__ xnorm, const float* __restrict__ cnorm,
    const int* __restrict__ labels,
    float* __restrict__ own, float* __restrict__ pmin) {
  // [buf][mat A=0/B=1][khalf][256 rows x 32 k] -- each khalf region is the
  // contiguous 16KB staging unit. 128 KiB total.
  __shared__ unsigned short lds[2][2][2][256 * 32];

  const int tid = threadIdx.x;
  const int lane = tid & 63;
  const int wid = tid >> 6;
  const int llo = lane & 15;
  const int lkc = lane >> 4;
  const int sw = ((lkc ^ (lane & 3)) << 4);  // swizzled 16B chunk byte offset

  int bid = blockIdx.x;
  int swz = (bid & 7) * (NWG / 8) + (bid >> 3);
  const int brow0 = (swz / NCB) * BM;
  const int bcol0 = (swz % NCB) * BN;
  const int wr = wid >> 2, wc = wid & 3;  // 2x4 wave grid: wave output 128x64

  f32x4 acc[8][4];
  #pragma unroll
  for (int m = 0; m < 8; m++)
    #pragma unroll
    for (int n = 0; n < 4; n++)
      acc[m][n] = (f32x4){0.f, 0.f, 0.f, 0.f};

  // prologue: t0 (h1..h4) -> buf0, t1 (h1..h3) -> buf1.  h1=A.kh0, h2=B.kh0,
  // h3=A.kh1, h4=B.kh1.  14 loads/wave issued; vmcnt(6) -> t0's 8 landed.
  stage_half(&lds[0][0][0][0], xb, brow0, 0, wid, lane);
  stage_half(&lds[0][1][0][0], cb, bcol0, 0, wid, lane);
  stage_half(&lds[0][0][1][0], xb, brow0, 32, wid, lane);
  stage_half(&lds[0][1][1][0], cb, bcol0, 32, wid, lane);
  stage_half(&lds[1][0][0][0], xb, brow0, 64, wid, lane);
  stage_half(&lds[1][1][0][0], cb, bcol0, 64, wid, lane);
  stage_half(&lds[1][0][1][0], xb, brow0, 96, wid, lane);
  asm volatile("s_waitcnt vmcnt(6)" ::: "memory");
  __builtin_amdgcn_s_barrier();

  bf16x8 afr[8];

  // steady-state iterations: phases 1-4 compute t (buf0), 5-8 compute t+1 (buf1).
  // Stage order per iter: t+1.h4 | t+2.h1 | t+2.h2 | t+2.h3+vmcnt(6) |
  //                       t+2.h4 | t+3.h1 | t+3.h2 | t+3.h3+vmcnt(6)
  // Each staged region's last LDS read is in the immediately preceding phase
  // (verified region-by-region), so DMA writes never race reads.
  for (int it = 0; it < NIT - 1; ++it) {
    const int t = 2 * it;
    const int k1 = (t + 1) * BK, k2 = (t + 2) * BK, k3 = (t + 3) * BK;
    PHASE(0, 0, 0, stage_half(&lds[1][1][1][0], cb, bcol0, k1 + 32, wid, lane), (void)0)
    PHASE(0, 0, 1, stage_half(&lds[0][0][0][0], xb, brow0, k2, wid, lane), (void)0)
    PHASE(0, 1, 0, stage_half(&lds[0][1][0][0], cb, bcol0, k2, wid, lane), (void)0)
    PHASE(0, 1, 1, stage_half(&lds[0][0][1][0], xb, brow0, k2 + 32, wid, lane),
          asm volatile("s_waitcnt vmcnt(6)" ::: "memory"))
    PHASE(1, 0, 0, stage_half(&lds[0][1][1][0], cb, bcol0, k2 + 32, wid, lane), (void)0)
    PHASE(1, 0, 1, stage_half(&lds[1][0][0][0], xb, brow0, k3, wid, lane), (void)0)
    PHASE(1, 1, 0, stage_half(&lds[1][1][0][0], cb, bcol0, k3, wid, lane), (void)0)
    PHASE(1, 1, 1, stage_half(&lds[1][0][1][0], xb, brow0, k3 + 32, wid, lane),
          asm volatile("s_waitcnt vmcnt(6)" ::: "memory"))
  }
  // peeled last iteration (t = NT-2): only t+1.h4 left to stage; drain at P4.
  {
    const int k1 = (NT - 1) * BK;
    PHASE(0, 0, 0, stage_half(&lds[1][1][1][0], cb, bcol0, k1 + 32, wid, lane), (void)0)
    PHASE(0, 0, 1, (void)0, (void)0)
    PHASE(0, 1, 0, (void)0, (void)0)
    PHASE(0, 1, 1, (void)0, asm volatile("s_waitcnt vmcnt(0)" ::: "memory"))
    PHASE(1, 0, 0, (void)0, (void)0)
    PHASE(1, 0, 1, (void)0, (void)0)
    PHASE(1, 1, 0, (void)0, (void)0)
    PHASE(1, 1, 1, (void)0, (void)0)
  }

  // ---- epilogue: dist = xn + cn - 2*dot; own-col; per-row min ----
  // C/D layout: col = lane&15, row = (lane>>4)*4 + reg  (m89-verified)
  float cnr[4];
  int coln[4];
  #pragma unroll
  for (int n = 0; n < 4; n++) {
    coln[n] = bcol0 + wc * 64 + n * 16 + llo;
    cnr[n] = cnorm[coln[n]];
  }
  const int cslot = bcol0 / 64 + wc;
  #pragma unroll
  for (int m = 0; m < 8; m++) {
    #pragma unroll
    for (int j = 0; j < 4; j++) {
      int row = brow0 + wr * 128 + m * 16 + lkc * 4 + j;
      float xn = xnorm[row];
      int lbl = labels[row];
      float rmin = 1e38f;
      #pragma unroll
      for (int n = 0; n < 4; n++) {
        float d = xn + cnr[n] - 2.0f * acc[m][n][j];
        if (coln[n] == lbl) own[row] = d;  // exactly one writer per row
        else rmin = fminf(rmin, d);
      }
      rmin = fminf(rmin, __shfl_xor(rmin, 1));
      rmin = fminf(rmin, __shfl_xor(rmin, 2));
      rmin = fminf(rmin, __shfl_xor(rmin, 4));
      rmin = fminf(rmin, __shfl_xor(rmin, 8));
      if (llo == 0) pmin[(size_t)row * NSLOT + cslot] = rmin;
    }
  }
}

// ---------------- fallback: reg-staged 128^2 fused GEMM (small ws) ----------------
constexpr int FBM = 128, FBK = 32;
constexpr int FNWG = (NB / FBM) * (NC / FBM);
__global__ __launch_bounds__(256) void gemm_fb_kernel(
    const float* __restrict__ xf, const float* __restrict__ cf,
    const float* __restrict__ xnorm, const float* __restrict__ cnorm,
    const int* __restrict__ labels,
    float* __restrict__ own, float* __restrict__ pmin) {
  __shared__ alignas(16) unsigned short lA[FBM * FBK];
  __shared__ alignas(16) unsigned short lB[FBM * FBK];
  const int tid = threadIdx.x, lane = tid & 63, wid = tid >> 6;
  int bid = blockIdx.x;
  int swz = (bid & 7) * (FNWG >> 3) + (bid >> 3);
  const int brow0 = (swz / (NC / FBM)) * FBM;
  const int bcol0 = (swz % (NC / FBM)) * FBM;
  const int wr = wid >> 1, wc = wid & 1;
  f32x4 acc[4][4];
  #pragma unroll
  for (int m = 0; m < 4; m++)
    #pragma unroll
    for (int n = 0; n < 4; n++) acc[m][n] = (f32x4){0.f, 0.f, 0.f, 0.f};
  for (int k0 = 0; k0 < ND; k0 += FBK) {
    __syncthreads();
    int ar = tid >> 1, ac = (tid & 1) << 4;
    const float* ga = xf + (size_t)(brow0 + ar) * ND + k0 + ac;
    const float* gb = cf + (size_t)(bcol0 + ar) * ND + k0 + ac;
    usvec8 ua[2], ub[2];
    #pragma unroll
    for (int h = 0; h < 2; h++) {
      float4 p = *(const float4*)(ga + h * 8), q = *(const float4*)(ga + h * 8 + 4);
      ua[h][0] = f2bf(p.x); ua[h][1] = f2bf(p.y); ua[h][2] = f2bf(p.z); ua[h][3] = f2bf(p.w);
      ua[h][4] = f2bf(q.x); ua[h][5] = f2bf(q.y); ua[h][6] = f2bf(q.z); ua[h][7] = f2bf(q.w);
      float4 r = *(const float4*)(gb + h * 8), s = *(const float4*)(gb + h * 8 + 4);
      ub[h][0] = f2bf(r.x); ub[h][1] = f2bf(r.y); ub[h][2] = f2bf(r.z); ub[h][3] = f2bf(r.w);
      ub[h][4] = f2bf(s.x); ub[h][5] = f2bf(s.y); ub[h][6] = f2bf(s.z); ub[h][7] = f2bf(s.w);
    }
    *(usvec8*)&lA[ar * FBK + ac] = ua[0];
    *(usvec8*)&lA[ar * FBK + ac + 8] = ua[1];
    *(usvec8*)&lB[ar * FBK + ac] = ub[0];
    *(usvec8*)&lB[ar * FBK + ac + 8] = ub[1];
    __syncthreads();
    bf16x8 af[4], bf[4];
    #pragma unroll
    for (int m = 0; m < 4; m++)
      af[m] = *(const bf16x8*)&lA[(wr * 64 + m * 16 + (lane & 15)) * FBK + (lane >> 4) * 8];
    #pragma unroll
    for (int n = 0; n < 4; n++)
      bf[n] = *(const bf16x8*)&lB[(wc * 64 + n * 16 + (lane & 15)) * FBK + (lane >> 4) * 8];
    #pragma unroll
    for (int m = 0; m < 4; m++)
      #pragma unroll
      for (int n = 0; n < 4; n++)
        acc[m][n] = __builtin_amdgcn_mfma_f32_16x16x32_bf16(af[m], bf[n], acc[m][n], 0, 0, 0);
  }
  const int llo = lane & 15, lhi = lane >> 4;
  float cnr[4];
  int coln[4];
  #pragma unroll
  for (int n = 0; n < 4; n++) {
    coln[n] = bcol0 + wc * 64 + n * 16 + llo;
    cnr[n] = cnorm[coln[n]];
  }
  const int cslot = bcol0 / 64 + wc;
  #pragma unroll
  for (int m = 0; m < 4; m++)
    #pragma unroll
    for (int j = 0; j < 4; j++) {
      int row = brow0 + wr * 64 + m * 16 + lhi * 4 + j;
      float xn = xnorm[row];
      int lbl = labels[row];
      float rmin = 1e38f;
      #pragma unroll
      for (int n = 0; n < 4; n++) {
        float d = xn + cnr[n] - 2.0f * acc[m][n][j];
        if (coln[n] == lbl) own[row] = d;
        else rmin = fminf(rmin, d);
      }
      rmin = fminf(rmin, __shfl_xor(rmin, 1));
      rmin = fminf(rmin, __shfl_xor(rmin, 2));
      rmin = fminf(rmin, __shfl_xor(rmin, 4));
      rmin = fminf(rmin, __shfl_xor(rmin, 8));
      if (llo == 0) pmin[(size_t)row * NSLOT + cslot] = rmin;
    }
}

// ---------------- final: hinge + deterministic sum ----------------
__global__ __launch_bounds__(256) void finalize_kernel(const float* __restrict__ own,
                                                       const float* __restrict__ pmin,
                                                       const float* __restrict__ margin,
                                                       const float* __restrict__ wgt,
                                                       float* __restrict__ partial) {
  int r = blockIdx.x * 256 + threadIdx.x;
  const float4* p4 = (const float4*)(pmin + (size_t)r * NSLOT);
  float mn = 1e38f;
  #pragma unroll
  for (int i = 0; i < NSLOT / 4; i++) {
    float4 v = p4[i];
    mn = fminf(mn, fminf(fminf(v.x, v.y), fminf(v.z, v.w)));
  }
  float W = *wgt;
  float h = fmaxf(*margin + W * own[r] - (1.0f - W) * mn, 0.0f);
  #pragma unroll
  for (int m = 1; m < 64; m <<= 1) h += __shfl_xor(h, m);
  __shared__ float red[4];
  int lane = threadIdx.x & 63, wid = threadIdx.x >> 6;
  if (lane == 0) red[wid] = h;
  __syncthreads();
  if (threadIdx.x == 0) partial[blockIdx.x] = red[0] + red[1] + red[2] + red[3];
}

__global__ void final2_kernel(const float* __restrict__ partial, float* __restrict__ out) {
  float s = (threadIdx.x < NB / 256) ? partial[threadIdx.x] : 0.f;
  #pragma unroll
  for (int m = 1; m < 64; m <<= 1) s += __shfl_xor(s, m);
  if (threadIdx.x == 0) out[0] = s * (1.0f / NB);
}

extern "C" void kernel_launch(void* const* d_in, const int* in_sizes, int n_in,
                              void* d_out, int out_size, void* d_ws, size_t ws_size,
                              hipStream_t stream) {
  const float* x = (const float*)d_in[0];
  const float* cen = (const float*)d_in[1];
  const int* labels = (const int*)d_in[2];
  const float* margin = (const float*)d_in[3];
  const float* wgt = (const float*)d_in[4];
  float* out = (float*)d_out;

  char* base = (char*)d_ws;
  size_t off = 0;
  auto alloc = [&](size_t bytes) {
    void* q = base + off;
    off = (off + bytes + 255) & ~(size_t)255;
    return q;
  };
  float* xnorm = (float*)alloc((size_t)NB * 4);
  float* cnorm = (float*)alloc((size_t)NC * 4);
  float* own = (float*)alloc((size_t)NB * 4);
  float* pmin = (float*)alloc((size_t)NB * NSLOT * 4);
  float* partial = (float*)alloc(64 * 4);
  unsigned short* xb = (unsigned short*)alloc((size_t)NB * ND * 2);
  unsigned short* cb = (unsigned short*)alloc((size_t)NC * ND * 2);
  size_t need_big = off;  // ~52.9 MB

  if (ws_size >= need_big) {
    prep_kernel<<<NB + NC, 256, 0, stream>>>(x, cen, xnorm, cnorm, xb, cb);
    gemm8_kernel<<<NWG, 512, 0, stream>>>(xb, cb, xnorm, cnorm, labels, own, pmin);
  } else {
    norms_kernel<<<NB + NC, 256, 0, stream>>>(x, cen, xnorm, cnorm);
    gemm_fb_kernel<<<FNWG, 256, 0, stream>>>(x, cen, xnorm, cnorm, labels, own, pmin);
  }
  finalize_kernel<<<NB / 256, 256, 0, stream>>>(own, pmin, margin, wgt, partial);
  final2_kernel<<<1, 64, 0, stream>>>(partial, out);
}

// Round 4
// 160.180 us; speedup vs baseline: 1.3154x; 1.0504x over previous
//
#include <hip/hip_runtime.h>
#include <hip/hip_bf16.h>
#include <cstdint>

// TripCenterLoss_min_margin: B=8192, C=4096, D=2048
// loss = mean_b max(margin + w*dist_own(b) - (1-w)*min_{c!=lbl} dist(b,c), 0)
constexpr int NB = 8192;
constexpr int NC = 4096;
constexpr int ND = 2048;

// ---- 8-phase 256x256 GEMM geometry ----
constexpr int BM = 256, BN = 256, BK = 64;
constexpr int NRB = NB / BM;    // 32
constexpr int NCB = NC / BN;    // 16
constexpr int NWG = NRB * NCB;  // 512  (%8==0 -> bijective XCD swizzle)
constexpr int NT = ND / BK;     // 32 K-tiles
constexpr int NIT = NT / 2;     // 16 iterations (2 K-tiles each)
constexpr int NSLOT = NC / 64;  // 64 pmin slots per row

typedef __attribute__((ext_vector_type(8))) __bf16 bf16x8;
typedef __attribute__((ext_vector_type(8))) unsigned short usvec8;
typedef __attribute__((ext_vector_type(4))) unsigned short usvec4;
typedef __attribute__((ext_vector_type(4))) float f32x4;

__device__ inline unsigned short f2bf(float f) {
  unsigned int u = __float_as_uint(f);
  u += 0x7fffu + ((u >> 16) & 1u);  // RNE
  return (unsigned short)(u >> 16);
}

// ---------------- fused norms + f32->bf16 convert ----------------
__global__ __launch_bounds__(256) void prep_kernel(const float* __restrict__ x,
                                                   const float* __restrict__ cen,
                                                   float* __restrict__ xnorm,
                                                   float* __restrict__ cnorm,
                                                   unsigned short* __restrict__ xb,
                                                   unsigned short* __restrict__ cb) {
  int row = blockIdx.x;
  const float* src;
  float* ndst;
  unsigned short* bdst;
  if (row < NB) { src = x + (size_t)row * ND; ndst = xnorm + row; bdst = xb + (size_t)row * ND; }
  else { row -= NB; src = cen + (size_t)row * ND; ndst = cnorm + row; bdst = cb + (size_t)row * ND; }
  float s = 0.f;
  #pragma unroll
  for (int it = 0; it < 2; it++) {
    int i = threadIdx.x * 4 + it * 1024;
    float4 v = *(const float4*)(src + i);
    s += v.x * v.x + v.y * v.y + v.z * v.z + v.w * v.w;
    usvec4 u;
    u[0] = f2bf(v.x); u[1] = f2bf(v.y); u[2] = f2bf(v.z); u[3] = f2bf(v.w);
    *(usvec4*)(bdst + i) = u;
  }
  #pragma unroll
  for (int m = 1; m < 64; m <<= 1) s += __shfl_xor(s, m);
  __shared__ float red[4];
  int lane = threadIdx.x & 63, wid = threadIdx.x >> 6;
  if (lane == 0) red[wid] = s;
  __syncthreads();
  if (threadIdx.x == 0) *ndst = red[0] + red[1] + red[2] + red[3];
}

// ---------------- norms only (fallback path) ----------------
__global__ __launch_bounds__(256) void norms_kernel(const float* __restrict__ x,
                                                    const float* __restrict__ cen,
                                                    float* __restrict__ xnorm,
                                                    float* __restrict__ cnorm) {
  int row = blockIdx.x;
  const float* src;
  float* dst;
  if (row < NB) { src = x + (size_t)row * ND; dst = xnorm + row; }
  else          { src = cen + (size_t)(row - NB) * ND; dst = cnorm + (row - NB); }
  float s = 0.f;
  #pragma unroll
  for (int it = 0; it < 2; it++) {
    int i = threadIdx.x * 4 + it * 1024;
    float4 v = *(const float4*)(src + i);
    s += v.x * v.x + v.y * v.y + v.z * v.z + v.w * v.w;
  }
  #pragma unroll
  for (int m = 1; m < 64; m <<= 1) s += __shfl_xor(s, m);
  __shared__ float red[4];
  int lane = threadIdx.x & 63, wid = threadIdx.x >> 6;
  if (lane == 0) red[wid] = s;
  __syncthreads();
  if (threadIdx.x == 0) *dst = red[0] + red[1] + red[2] + red[3];
}

// ---------------- async global->LDS ----------------
__device__ inline void gload_lds16(const void* g, void* lds) {
  __builtin_amdgcn_global_load_lds(
      (const __attribute__((address_space(1))) unsigned int*)g,
      (__attribute__((address_space(3))) unsigned int*)lds, 16, 0, 0);
}

// Stage one half-tile (256 rows x 32 k, 16KB) into a contiguous LDS region.
// LDS dest is LINEAR (base + chunk*16); the XOR swizzle is applied by
// permuting the GLOBAL source address (involution), per rule 21.
// Bank math (64B rows, 16B chunks): bank_start(row,pc) = (row&1)*16 + 4*pc.
// Storing logical kc at pc = kc ^ ((row>>1)&3) makes any 8 consecutive
// reading lanes (rows r..r+7, same logical kc) hit 8 DISTINCT 16B slots
// covering all 32 banks -> conflict-free ds_read_b128.
__device__ __forceinline__ void stage_half(unsigned short* reg, const unsigned short* gsrc,
                                           int row0, int kcol0, int wid, int lane) {
  #pragma unroll
  for (int i = 0; i < 2; i++) {
    int c = (wid * 2 + i) * 64 + lane;        // chunk index 0..1023
    int row = c >> 2;                         // 4 chunks (64B) per row
    int kc = (c & 3) ^ ((row >> 1) & 3);      // logical k-chunk at this physical slot
    gload_lds16(gsrc + (size_t)(row0 + row) * ND + kcol0 + kc * 8,
                (char*)reg + (size_t)c * 16);
  }
}

// One phase: ds-read frag subtile | issue 1 half-tile stage | barrier |
// lgkmcnt(0) | setprio(1) | 16 MFMA | setprio(0) | [vmcnt] | barrier.
#define PHASE(BUF, S, NH, STAGE_STMT, VM_STMT)                                          \
  {                                                                                     \
    const char* Ar = (const char*)&lds[BUF][0][S][0];                                   \
    const char* Br = (const char*)&lds[BUF][1][S][0];                                   \
    if (NH == 0) {                                                                      \
      _Pragma("unroll") for (int m = 0; m < 8; m++)                                     \
          afr[m] = *(const bf16x8*)(Ar + (wr * 128 + m * 16 + llo) * 64 + sw);          \
    }                                                                                   \
    bf16x8 b0 = *(const bf16x8*)(Br + (wc * 64 + (NH * 2 + 0) * 16 + llo) * 64 + sw);   \
    bf16x8 b1 = *(const bf16x8*)(Br + (wc * 64 + (NH * 2 + 1) * 16 + llo) * 64 + sw);   \
    STAGE_STMT;                                                                         \
    __builtin_amdgcn_s_barrier();                                                       \
    asm volatile("s_waitcnt lgkmcnt(0)" ::: "memory");                                  \
    __builtin_amdgcn_sched_barrier(0);                                                  \
    __builtin_amdgcn_s_setprio(1);                                                      \
    _Pragma("unroll") for (int m = 0; m < 8; m++) {                                     \
      acc[m][NH * 2 + 0] = __builtin_amdgcn_mfma_f32_16x16x32_bf16(                     \
          afr[m], b0, acc[m][NH * 2 + 0], 0, 0, 0);                                     \
      acc[m][NH * 2 + 1] = __builtin_amdgcn_mfma_f32_16x16x32_bf16(                     \
          afr[m], b1, acc[m][NH * 2 + 1], 0, 0, 0);                                     \
    }                                                                                   \
    __builtin_amdgcn_s_setprio(0);                                                      \
    VM_STMT;                                                                            \
    __builtin_amdgcn_s_barrier();                                                       \
  }

// ---------------- 8-phase 256^2 fused GEMM + row-min + own-dist ----------------
__global__ __launch_bounds__(512, 2) void gemm8_kernel(
    const unsigned short* __restrict__ xb, const unsigned short* __restrict__ cb,
    const float* __restrict__ xnorm, const float* __restrict__ cnorm,
    const int* __restrict__ labels,
    float* __restrict__ own, float* __restrict__ pmin) {
  // [buf][mat A=0/B=1][khalf][256 rows x 32 k] -- each khalf region is the
  // contiguous 16KB staging unit. 128 KiB total.
  __shared__ unsigned short lds[2][2][2][256 * 32];

  const int tid = threadIdx.x;
  const int lane = tid & 63;
  const int wid = tid >> 6;
  const int llo = lane & 15;
  const int lkc = lane >> 4;
  // swizzled 16B chunk byte offset: physical chunk = lkc ^ ((row>>1)&3);
  // frag rows are llo + 16*m, and (16m>>1)&3 == 0, so llo alone determines it.
  const int sw = ((lkc ^ ((llo >> 1) & 3)) << 4);

  int bid = blockIdx.x;
  int swz = (bid & 7) * (NWG / 8) + (bid >> 3);
  const int brow0 = (swz / NCB) * BM;
  const int bcol0 = (swz % NCB) * BN;
  const int wr = wid >> 2, wc = wid & 3;  // 2x4 wave grid: wave output 128x64

  f32x4 acc[8][4];
  #pragma unroll
  for (int m = 0; m < 8; m++)
    #pragma unroll
    for (int n = 0; n < 4; n++)
      acc[m][n] = (f32x4){0.f, 0.f, 0.f, 0.f};

  // prologue: t0 (h1..h4) -> buf0, t1 (h1..h3) -> buf1.  h1=A.kh0, h2=B.kh0,
  // h3=A.kh1, h4=B.kh1.  14 loads/wave issued; vmcnt(6) -> t0's 8 landed.
  stage_half(&lds[0][0][0][0], xb, brow0, 0, wid, lane);
  stage_half(&lds[0][1][0][0], cb, bcol0, 0, wid, lane);
  stage_half(&lds[0][0][1][0], xb, brow0, 32, wid, lane);
  stage_half(&lds[0][1][1][0], cb, bcol0, 32, wid, lane);
  stage_half(&lds[1][0][0][0], xb, brow0, 64, wid, lane);
  stage_half(&lds[1][1][0][0], cb, bcol0, 64, wid, lane);
  stage_half(&lds[1][0][1][0], xb, brow0, 96, wid, lane);
  asm volatile("s_waitcnt vmcnt(6)" ::: "memory");
  __builtin_amdgcn_s_barrier();

  bf16x8 afr[8];

  // steady-state iterations: phases 1-4 compute t (buf0), 5-8 compute t+1 (buf1).
  // Stage order per iter: t+1.h4 | t+2.h1 | t+2.h2 | t+2.h3+vmcnt(6) |
  //                       t+2.h4 | t+3.h1 | t+3.h2 | t+3.h3+vmcnt(6)
  // Each staged region's last LDS read is in the immediately preceding phase
  // (verified region-by-region), so DMA writes never race reads.
  for (int it = 0; it < NIT - 1; ++it) {
    const int t = 2 * it;
    const int k1 = (t + 1) * BK, k2 = (t + 2) * BK, k3 = (t + 3) * BK;
    PHASE(0, 0, 0, stage_half(&lds[1][1][1][0], cb, bcol0, k1 + 32, wid, lane), (void)0)
    PHASE(0, 0, 1, stage_half(&lds[0][0][0][0], xb, brow0, k2, wid, lane), (void)0)
    PHASE(0, 1, 0, stage_half(&lds[0][1][0][0], cb, bcol0, k2, wid, lane), (void)0)
    PHASE(0, 1, 1, stage_half(&lds[0][0][1][0], xb, brow0, k2 + 32, wid, lane),
          asm volatile("s_waitcnt vmcnt(6)" ::: "memory"))
    PHASE(1, 0, 0, stage_half(&lds[0][1][1][0], cb, bcol0, k2 + 32, wid, lane), (void)0)
    PHASE(1, 0, 1, stage_half(&lds[1][0][0][0], xb, brow0, k3, wid, lane), (void)0)
    PHASE(1, 1, 0, stage_half(&lds[1][1][0][0], cb, bcol0, k3, wid, lane), (void)0)
    PHASE(1, 1, 1, stage_half(&lds[1][0][1][0], xb, brow0, k3 + 32, wid, lane),
          asm volatile("s_waitcnt vmcnt(6)" ::: "memory"))
  }
  // peeled last iteration (t = NT-2): only t+1.h4 left to stage; drain at P4.
  {
    const int k1 = (NT - 1) * BK;
    PHASE(0, 0, 0, stage_half(&lds[1][1][1][0], cb, bcol0, k1 + 32, wid, lane), (void)0)
    PHASE(0, 0, 1, (void)0, (void)0)
    PHASE(0, 1, 0, (void)0, (void)0)
    PHASE(0, 1, 1, (void)0, asm volatile("s_waitcnt vmcnt(0)" ::: "memory"))
    PHASE(1, 0, 0, (void)0, (void)0)
    PHASE(1, 0, 1, (void)0, (void)0)
    PHASE(1, 1, 0, (void)0, (void)0)
    PHASE(1, 1, 1, (void)0, (void)0)
  }

  // ---- epilogue: dist = xn + cn - 2*dot; own-col; per-row min ----
  // C/D layout: col = lane&15, row = (lane>>4)*4 + reg  (m89-verified)
  float cnr[4];
  int coln[4];
  #pragma unroll
  for (int n = 0; n < 4; n++) {
    coln[n] = bcol0 + wc * 64 + n * 16 + llo;
    cnr[n] = cnorm[coln[n]];
  }
  const int cslot = bcol0 / 64 + wc;
  #pragma unroll
  for (int m = 0; m < 8; m++) {
    #pragma unroll
    for (int j = 0; j < 4; j++) {
      int row = brow0 + wr * 128 + m * 16 + lkc * 4 + j;
      float xn = xnorm[row];
      int lbl = labels[row];
      float rmin = 1e38f;
      #pragma unroll
      for (int n = 0; n < 4; n++) {
        float d = xn + cnr[n] - 2.0f * acc[m][n][j];
        if (coln[n] == lbl) own[row] = d;  // exactly one writer per row
        else rmin = fminf(rmin, d);
      }
      rmin = fminf(rmin, __shfl_xor(rmin, 1));
      rmin = fminf(rmin, __shfl_xor(rmin, 2));
      rmin = fminf(rmin, __shfl_xor(rmin, 4));
      rmin = fminf(rmin, __shfl_xor(rmin, 8));
      if (llo == 0) pmin[(size_t)row * NSLOT + cslot] = rmin;
    }
  }
}

// ---------------- fallback: reg-staged 128^2 fused GEMM (small ws) ----------------
constexpr int FBM = 128, FBK = 32;
constexpr int FNWG = (NB / FBM) * (NC / FBM);
__global__ __launch_bounds__(256) void gemm_fb_kernel(
    const float* __restrict__ xf, const float* __restrict__ cf,
    const float* __restrict__ xnorm, const float* __restrict__ cnorm,
    const int* __restrict__ labels,
    float* __restrict__ own, float* __restrict__ pmin) {
  __shared__ alignas(16) unsigned short lA[FBM * FBK];
  __shared__ alignas(16) unsigned short lB[FBM * FBK];
  const int tid = threadIdx.x, lane = tid & 63, wid = tid >> 6;
  int bid = blockIdx.x;
  int swz = (bid & 7) * (FNWG >> 3) + (bid >> 3);
  const int brow0 = (swz / (NC / FBM)) * FBM;
  const int bcol0 = (swz % (NC / FBM)) * FBM;
  const int wr = wid >> 1, wc = wid & 1;
  f32x4 acc[4][4];
  #pragma unroll
  for (int m = 0; m < 4; m++)
    #pragma unroll
    for (int n = 0; n < 4; n++) acc[m][n] = (f32x4){0.f, 0.f, 0.f, 0.f};
  for (int k0 = 0; k0 < ND; k0 += FBK) {
    __syncthreads();
    int ar = tid >> 1, ac = (tid & 1) << 4;
    const float* ga = xf + (size_t)(brow0 + ar) * ND + k0 + ac;
    const float* gb = cf + (size_t)(bcol0 + ar) * ND + k0 + ac;
    usvec8 ua[2], ub[2];
    #pragma unroll
    for (int h = 0; h < 2; h++) {
      float4 p = *(const float4*)(ga + h * 8), q = *(const float4*)(ga + h * 8 + 4);
      ua[h][0] = f2bf(p.x); ua[h][1] = f2bf(p.y); ua[h][2] = f2bf(p.z); ua[h][3] = f2bf(p.w);
      ua[h][4] = f2bf(q.x); ua[h][5] = f2bf(q.y); ua[h][6] = f2bf(q.z); ua[h][7] = f2bf(q.w);
      float4 r = *(const float4*)(gb + h * 8), s = *(const float4*)(gb + h * 8 + 4);
      ub[h][0] = f2bf(r.x); ub[h][1] = f2bf(r.y); ub[h][2] = f2bf(r.z); ub[h][3] = f2bf(r.w);
      ub[h][4] = f2bf(s.x); ub[h][5] = f2bf(s.y); ub[h][6] = f2bf(s.z); ub[h][7] = f2bf(s.w);
    }
    *(usvec8*)&lA[ar * FBK + ac] = ua[0];
    *(usvec8*)&lA[ar * FBK + ac + 8] = ua[1];
    *(usvec8*)&lB[ar * FBK + ac] = ub[0];
    *(usvec8*)&lB[ar * FBK + ac + 8] = ub[1];
    __syncthreads();
    bf16x8 af[4], bf[4];
    #pragma unroll
    for (int m = 0; m < 4; m++)
      af[m] = *(const bf16x8*)&lA[(wr * 64 + m * 16 + (lane & 15)) * FBK + (lane >> 4) * 8];
    #pragma unroll
    for (int n = 0; n < 4; n++)
      bf[n] = *(const bf16x8*)&lB[(wc * 64 + n * 16 + (lane & 15)) * FBK + (lane >> 4) * 8];
    #pragma unroll
    for (int m = 0; m < 4; m++)
      #pragma unroll
      for (int n = 0; n < 4; n++)
        acc[m][n] = __builtin_amdgcn_mfma_f32_16x16x32_bf16(af[m], bf[n], acc[m][n], 0, 0, 0);
  }
  const int llo = lane & 15, lhi = lane >> 4;
  float cnr[4];
  int coln[4];
  #pragma unroll
  for (int n = 0; n < 4; n++) {
    coln[n] = bcol0 + wc * 64 + n * 16 + llo;
    cnr[n] = cnorm[coln[n]];
  }
  const int cslot = bcol0 / 64 + wc;
  #pragma unroll
  for (int m = 0; m < 4; m++)
    #pragma unroll
    for (int j = 0; j < 4; j++) {
      int row = brow0 + wr * 64 + m * 16 + lhi * 4 + j;
      float xn = xnorm[row];
      int lbl = labels[row];
      float rmin = 1e38f;
      #pragma unroll
      for (int n = 0; n < 4; n++) {
        float d = xn + cnr[n] - 2.0f * acc[m][n][j];
        if (coln[n] == lbl) own[row] = d;
        else rmin = fminf(rmin, d);
      }
      rmin = fminf(rmin, __shfl_xor(rmin, 1));
      rmin = fminf(rmin, __shfl_xor(rmin, 2));
      rmin = fminf(rmin, __shfl_xor(rmin, 4));
      rmin = fminf(rmin, __shfl_xor(rmin, 8));
      if (llo == 0) pmin[(size_t)row * NSLOT + cslot] = rmin;
    }
}

// ---------------- final: hinge + deterministic sum ----------------
__global__ __launch_bounds__(256) void finalize_kernel(const float* __restrict__ own,
                                                       const float* __restrict__ pmin,
                                                       const float* __restrict__ margin,
                                                       const float* __restrict__ wgt,
                                                       float* __restrict__ partial) {
  int r = blockIdx.x * 256 + threadIdx.x;
  const float4* p4 = (const float4*)(pmin + (size_t)r * NSLOT);
  float mn = 1e38f;
  #pragma unroll
  for (int i = 0; i < NSLOT / 4; i++) {
    float4 v = p4[i];
    mn = fminf(mn, fminf(fminf(v.x, v.y), fminf(v.z, v.w)));
  }
  float W = *wgt;
  float h = fmaxf(*margin + W * own[r] - (1.0f - W) * mn, 0.0f);
  #pragma unroll
  for (int m = 1; m < 64; m <<= 1) h += __shfl_xor(h, m);
  __shared__ float red[4];
  int lane = threadIdx.x & 63, wid = threadIdx.x >> 6;
  if (lane == 0) red[wid] = h;
  __syncthreads();
  if (threadIdx.x == 0) partial[blockIdx.x] = red[0] + red[1] + red[2] + red[3];
}

__global__ void final2_kernel(const float* __restrict__ partial, float* __restrict__ out) {
  float s = (threadIdx.x < NB / 256) ? partial[threadIdx.x] : 0.f;
  #pragma unroll
  for (int m = 1; m < 64; m <<= 1) s += __shfl_xor(s, m);
  if (threadIdx.x == 0) out[0] = s * (1.0f / NB);
}

extern "C" void kernel_launch(void* const* d_in, const int* in_sizes, int n_in,
                              void* d_out, int out_size, void* d_ws, size_t ws_size,
                              hipStream_t stream) {
  const float* x = (const float*)d_in[0];
  const float* cen = (const float*)d_in[1];
  const int* labels = (const int*)d_in[2];
  const float* margin = (const float*)d_in[3];
  const float* wgt = (const float*)d_in[4];
  float* out = (float*)d_out;

  char* base = (char*)d_ws;
  size_t off = 0;
  auto alloc = [&](size_t bytes) {
    void* q = base + off;
    off = (off + bytes + 255) & ~(size_t)255;
    return q;
  };
  float* xnorm = (float*)alloc((size_t)NB * 4);
  float* cnorm = (float*)alloc((size_t)NC * 4);
  float* own = (float*)alloc((size_t)NB * 4);
  float* pmin = (float*)alloc((size_t)NB * NSLOT * 4);
  float* partial = (float*)alloc(64 * 4);
  unsigned short* xb = (unsigned short*)alloc((size_t)NB * ND * 2);
  unsigned short* cb = (unsigned short*)alloc((size_t)NC * ND * 2);
  size_t need_big = off;  // ~52.9 MB

  if (ws_size >= need_big) {
    prep_kernel<<<NB + NC, 256, 0, stream>>>(x, cen, xnorm, cnorm, xb, cb);
    gemm8_kernel<<<NWG, 512, 0, stream>>>(xb, cb, xnorm, cnorm, labels, own, pmin);
  } else {
    norms_kernel<<<NB + NC, 256, 0, stream>>>(x, cen, xnorm, cnorm);
    gemm_fb_kernel<<<FNWG, 256, 0, stream>>>(x, cen, xnorm, cnorm, labels, own, pmin);
  }
  finalize_kernel<<<NB / 256, 256, 0, stream>>>(own, pmin, margin, wgt, partial);
  final2_kernel<<<1, 64, 0, stream>>>(partial, out);
}